// Round 15
// baseline (164.302 us; speedup 1.0000x reference)
//
#include <hip/hip_runtime.h>
#include <hip/hip_bf16.h>
#include <stdint.h>

// MegaNeRF fused MoE-MLP for MI355X (gfx950).  Round 15.
// E=8 experts, MLP 90->256->256->256->4, N=131072 points, inverse-distance gating.
//
// Round-15 = r14 (151 us; fused 104) with the fused wave tile changed
// wch(8)x wpt(1) -> wch(4) x wpt(2): wave = 64ch x 32pt, acc[4][2] (same 32
// regs).  Each wave reads h for only 32 points -> LDS h-read volume HALVES
// (was co-saturating with MFMA at ~60 us each).  Weight fetch duplicated 2x
// across the wpt pair (L2-served).  Store algebra for this tiling verified in
// r9; weight fragment layout already supports it (wch4 = 2 adjacent wch8
// blocks at imm offsets).  Pre-pass and L4||L1 overlap unchanged from r14.

#define NE    8
#define FIN   90
#define HD    256
#define NOUT  4
#define XC    93          // 3 + FIN columns in x

#define MT        64      // points per block
#define NTHREADS  512     // 8 waves: wch(4) x wpt(2)

#define KQ1   3           // ceil(90/32) -> K padded to 96
#define KQH   8           // 256/32

#define W1_ELEMS (NE*8*KQ1*2*512)   // 196608
#define W2_ELEMS (NE*8*KQH*2*512)   // 524288
#define WO_ELEMS (NE*KQH*512)       // 32768  (OUT padded 4->16)
#define WTOT     (W1_ELEMS + 2*W2_ELEMS + WO_ELEMS)   // 1277952 elems

typedef __attribute__((ext_vector_type(8))) short bf16x8;
typedef __attribute__((ext_vector_type(4))) short bf16x4;
typedef __attribute__((ext_vector_type(4))) float f32x4;

__device__ __forceinline__ unsigned short f2bf(float f) {   // cold path only
  union { float f; uint32_t u; } v; v.f = f;
  v.u += 0x7fffu + ((v.u >> 16) & 1u);   // RNE
  return (unsigned short)(v.u >> 16);
}

__device__ __forceinline__ short relu_bf(float f) {         // hot epilogue
  __hip_bfloat16 t = __float2bfloat16(fmaxf(f, 0.f));
  return __builtin_bit_cast(short, t);
}

// wave-uniform pointer -> SGPR (HK technique: readfirstlane base hoisting)
__device__ __forceinline__ const unsigned short* rf_ptr(const unsigned short* p) {
  uint64_t u = (uint64_t)(uintptr_t)p;
  uint32_t lo = __builtin_amdgcn_readfirstlane((uint32_t)u);
  uint32_t hi = __builtin_amdgcn_readfirstlane((uint32_t)(u >> 32));
  return (const unsigned short*)(uintptr_t)(((uint64_t)hi << 32) | lo);
}

// ---------------------------------------------------------------------------
// Weight conversion (r10-r14, verified) + counts zeroing in block 0.
//   W1:    g = ((e*8 + wch8)*3 + kq)*2 + cf ;  W2/W3: g = ((e*8+wch8)*8+kq)*2+cf
//   Wo:    g = e*8 + kq
// elem (lane,j) = W[k = kq*32+(lane>>4)*8+j][n = wch8*32 + cf*16 + (lane&15)].
// ---------------------------------------------------------------------------
__global__ __launch_bounds__(256)
void convert_weights(const float* __restrict__ W1, const float* __restrict__ W2,
                     const float* __restrict__ W3, const float* __restrict__ Wo,
                     unsigned short* __restrict__ ws, int* __restrict__ counts) {
  if (blockIdx.x == 0) counts[threadIdx.x] = 0;
  int idx = blockIdx.x * 256 + threadIdx.x;
  int j = idx & 7;
  int lane = (idx >> 3) & 63;
  int n16 = lane & 15;
  int kof = ((lane >> 4) << 3) + j;
  if (idx < W1_ELEMS) {
    int g = idx >> 9;
    int cf = g & 1; int t = g >> 1;
    int kq = t % 3; t /= 3;
    int wch = t & 7; int e = t >> 3;
    int n = wch*32 + cf*16 + n16, k = kq*32 + kof;
    float v = (k < FIN) ? W1[(e*FIN + k)*HD + n] : 0.f;
    ws[idx] = f2bf(v);
  } else if (idx < W1_ELEMS + 2*W2_ELEMS) {
    int u = idx - W1_ELEMS;
    const float* W = (u < W2_ELEMS) ? W2 : W3;
    int uu = (u < W2_ELEMS) ? u : (u - W2_ELEMS);
    int g = uu >> 9;
    int cf = g & 1; int t = g >> 1;
    int kq = t & 7; t >>= 3;
    int wch = t & 7; int e = t >> 3;
    int n = wch*32 + cf*16 + n16, k = kq*32 + kof;
    ws[idx] = f2bf(W[(e*HD + k)*HD + n]);
  } else if (idx < WTOT) {
    int t = idx - (W1_ELEMS + 2*W2_ELEMS);
    int g = t >> 9;
    int kq = g & 7; int e = g >> 3;
    int k = kq*32 + kof;
    float v = (n16 < NOUT) ? Wo[(e*HD + k)*NOUT + n16] : 0.f;
    ws[idx] = f2bf(v);
  }
}

// --------------------------- compaction pre-pass ---------------------------
// Per-block LDS histogram + one global atomic per nonzero bucket (G12).
__global__ __launch_bounds__(256)
void gate_mask(const float* __restrict__ x, const float* __restrict__ cent,
               unsigned int* __restrict__ rankmask, int* __restrict__ counts, int N) {
  __shared__ int lcnt[256];
  __shared__ int lbase[256];
  const int tid = threadIdx.x;
  const int p = blockIdx.x * 256 + tid;
  lcnt[tid] = 0;
  __syncthreads();

  unsigned int mask = 0; int lr = 0;
  if (p < N) {
    float px = x[(size_t)p*XC + 1], py = x[(size_t)p*XC + 2];
    float d[NE]; float mind = 3.4e38f;
#pragma unroll
    for (int e = 0; e < NE; ++e) {
      float dx = px - cent[e*3 + 1];
      float dy = py - cent[e*3 + 2];
      d[e] = __fsqrt_rn(__fmul_rn(dx, dx) + __fmul_rn(dy, dy));
      mind = fminf(mind, d[e]);
    }
    float m = 1.5f * mind;
#pragma unroll
    for (int e = 0; e < NE; ++e)
      if (!(d[e] > m)) mask |= (1u << e);        // same predicate as inv>0
    lr = atomicAdd(&lcnt[mask], 1);              // LDS atomic: fast
  }
  __syncthreads();
  if (lcnt[tid] > 0)
    lbase[tid] = atomicAdd(&counts[tid], lcnt[tid]);   // few per block, uncontended
  __syncthreads();
  if (p < N)
    rankmask[p] = ((unsigned int)(lbase[mask] + lr) << 8) | mask;
}

// Parallel bucket-offset scan, popcount-DESC order.
__global__ __launch_bounds__(256)
void scan_offsets(const int* __restrict__ counts, int* __restrict__ offsets) {
  __shared__ int cnt[256];
  __shared__ int key[256];
  const int m = threadIdx.x;
  cnt[m] = counts[m];
  key[m] = ((8 - __popc((unsigned)m)) << 8) | m;
  __syncthreads();
  const int my = key[m];
  int acc = 0;
  for (int i = 0; i < 256; ++i)
    if (key[i] < my) acc += cnt[i];
  offsets[m] = acc;
}

__global__ __launch_bounds__(256)
void scatter_perm(const unsigned int* __restrict__ rankmask,
                  const int* __restrict__ offsets, int* __restrict__ perm, int N) {
  int p = blockIdx.x * 256 + threadIdx.x;
  if (p >= N) return;
  unsigned int v = rankmask[p];
  perm[offsets[v & 255u] + (int)(v >> 8)] = p;
}

// ---------------------------------------------------------------------------
// X conversion, gathered through perm (r11-r14, verified).
// ---------------------------------------------------------------------------
__global__ __launch_bounds__(256)
void convert_x(const float* __restrict__ x, unsigned short* __restrict__ xs,
               const int* __restrict__ perm, int nfrag) {
  int idx = blockIdx.x * 256 + threadIdx.x;
  if (idx >= nfrag * 512) return;
  int j = idx & 7;
  int lane = (idx >> 3) & 63;
  int f = idx >> 9;
  int kq = f % KQ1;
  int r16 = f / KQ1;
  int row = r16*16 + (lane & 15);
  int p = perm[row];
  int k = kq*32 + ((lane >> 4) << 3) + j;
  float v = (k < FIN) ? x[(size_t)p*XC + 3 + k] : 0.f;
  xs[idx] = f2bf(v);
}

// ---------------------------------------------------------------------------
// Epilogue (r9 algebra, verified): relu + pack 4 consecutive channels -> one
// b64 store into dst's B-frag layout.  Wave = 64ch(wch4) x 32pt(wpt).
// D: point m = wpt*32+pf*16+l15, channel c = wch*64+cf*16+l4*4+j.
// base = wpt*8192 + wch*1024 + l15*8 + (l4>>1)*128 + (l4&1)*4;
// offsets pf*4096 + (cf>>1)*512 + (cf&1)*256.  4 bank phases -> conflict-free.
// ---------------------------------------------------------------------------
__device__ __forceinline__ void store_hB(f32x4 (&acc)[4][2], unsigned short* dst,
                                         int wch, int wpt, int l15, int l4) {
  unsigned short* base = dst + wpt*8192 + wch*1024 + l15*8 + (l4>>1)*128 + (l4&1)*4;
#pragma unroll
  for (int cf = 0; cf < 4; ++cf)
#pragma unroll
    for (int pf = 0; pf < 2; ++pf) {
      bf16x4 s;
      s.x = relu_bf(acc[cf][pf][0]);
      s.y = relu_bf(acc[cf][pf][1]);
      s.z = relu_bf(acc[cf][pf][2]);
      s.w = relu_bf(acc[cf][pf][3]);
      *reinterpret_cast<bf16x4*>(base + pf*4096 + (cf>>1)*512 + (cf&1)*256) = s;
    }
}

// One hidden layer src -> dst (ping-pong; caller places ONE barrier after).
// fw = layer base + e*65536 + wch*16384 (two adjacent wch8 blocks of 8192).
__device__ __forceinline__ void layerH(const unsigned short* src, unsigned short* dst,
                                       const unsigned short* __restrict__ fw,
                                       const float* __restrict__ bias,
                                       int wch, int wpt, int l15, int l4, int lane) {
  f32x4 acc[4][2];   // [cf][pf]
#pragma unroll
  for (int cf = 0; cf < 4; ++cf) {
    f32x4 bv = *reinterpret_cast<const f32x4*>(&bias[wch*64 + cf*16 + l4*4]);
    acc[cf][0] = bv; acc[cf][1] = bv;
  }

  const unsigned short* fwW = rf_ptr(fw) + lane*8;   // SGPR base + lane off
  const unsigned short* rb  = src + wpt*8192 + lane*8;
#pragma unroll
  for (int kq = 0; kq < KQH; ++kq) {
    bf16x8 aw[4];
    aw[0] = *(const bf16x8*)(fwW + kq*1024);
    aw[1] = *(const bf16x8*)(fwW + kq*1024 + 512);
    aw[2] = *(const bf16x8*)(fwW + 8192 + kq*1024);
    aw[3] = *(const bf16x8*)(fwW + 8192 + kq*1024 + 512);
#pragma unroll
    for (int pf = 0; pf < 2; ++pf) {
      bf16x8 bh = *(const bf16x8*)(rb + pf*4096 + kq*512);
#pragma unroll
      for (int cf = 0; cf < 4; ++cf)
        acc[cf][pf] = __builtin_amdgcn_mfma_f32_16x16x32_bf16(aw[cf], bh, acc[cf][pf], 0, 0, 0);
    }
  }
  store_hB(acc, dst, wch, wpt, l15, l4);
}

template<bool XSTAGED>
__global__ __launch_bounds__(NTHREADS)
void meganerf_fused(const float* __restrict__ x, const float* __restrict__ cent,
                    const float* __restrict__ b1, const float* __restrict__ b2,
                    const float* __restrict__ b3, const float* __restrict__ bo,
                    const unsigned short* __restrict__ wf,
                    const unsigned short* __restrict__ xs,
                    const int* __restrict__ perm,
                    float* __restrict__ out) {
  __shared__ unsigned short hA[4 * KQH * 512];  // 32768 B: [mtile][kq][lane][8]
  __shared__ unsigned short hBuf[4 * KQH * 512];// 32768 B (ping-pong partner)
  __shared__ float wcl[MT * NE];                // 2048 B
  __shared__ int flags[NE];                     // block-uniform expert-active flags

  const int tid = threadIdx.x;
  const int lane = tid & 63;
  const int wv = tid >> 6;      // 0..7
  const int wch = wv >> 1;      // channel group 0..3 (64 channels each)
  const int wpt = wv & 1;       // point group 0..1 (32 points each)
  const int l15 = lane & 15, l4 = lane >> 4;
  const int row0 = blockIdx.x * MT;

  if (tid < NE) flags[tid] = 0;
  __syncthreads();

  // --- cluster weights (strict IEEE f32, no contraction: must bit-match np) ---
  if (tid < MT) {
    const int p = perm[row0 + tid];
    float px = x[(size_t)p*XC + 1], py = x[(size_t)p*XC + 2];
    float d[NE]; float mind = 3.4e38f;
#pragma unroll
    for (int e = 0; e < NE; ++e) {
      float dx = px - cent[e*3 + 1];
      float dy = py - cent[e*3 + 2];
      d[e] = __fsqrt_rn(__fmul_rn(dx, dx) + __fmul_rn(dy, dy));
      mind = fminf(mind, d[e]);
    }
    float m = 1.5f * mind, s = 0.f, inv[NE];
#pragma unroll
    for (int e = 0; e < NE; ++e) {
      float iv = (d[e] > m) ? 0.f : 1.f / (d[e] + 1e-8f);
      inv[e] = iv; s += iv;
    }
#pragma unroll
    for (int e = 0; e < NE; ++e) {
      wcl[tid*NE + e] = inv[e] / s;
      if (inv[e] > 0.f) flags[e] = 1;   // benign same-value race
    }
  }
  __syncthreads();

  const unsigned short* fw1 = wf;
  const unsigned short* fw2 = wf + W1_ELEMS;
  const unsigned short* fw3 = fw2 + W2_ELEMS;
  const unsigned short* fwo = fw3 + W2_ELEMS;
  // staged X base: this wave's two 16-row tiles (mtiles wpt*2, wpt*2+1)
  const unsigned short* xsb = xs + ((size_t)(blockIdx.x*4 + wpt*2)*KQ1)*512 + lane*8;

  float og[NOUT] = {0.f, 0.f, 0.f, 0.f};   // gated outputs (waves 0-3, l4==0)
  int pe = -1;                             // pending expert awaiting its L4
  int pb = 0;                              // buffer index holding pending h

  for (int e = 0; e < NE; ++e) {
    if (!flags[e]) continue;               // block-uniform: exact zero contribution

    unsigned short* bufP = (pb == 0) ? hA : hBuf;    // pending L4 input
    unsigned short* bufC = (pe >= 0) ? ((pb == 0) ? hBuf : hA) : hA;  // L1 output
    unsigned short* bufO = (bufC == hA) ? hBuf : hA; // L2 output

    // ---- L4(pending) on waves 0-3 (reads bufP)  OVERLAPPED with
    //      L1(e) on all waves (writes bufC != bufP): no barrier between ----
    if (pe >= 0 && wv < 4) {
      const unsigned short* fwoE = rf_ptr(fwo + pe*4096) + lane*8;
      f32x4 acc = {0.f, 0.f, 0.f, 0.f};
#pragma unroll
      for (int kq = 0; kq < KQH; ++kq) {
        bf16x8 aw = *(const bf16x8*)(fwoE + kq*512);
        bf16x8 bh = *(const bf16x8*)(bufP + wv*4096 + kq*512 + lane*8);
        acc = __builtin_amdgcn_mfma_f32_16x16x32_bf16(aw, bh, acc, 0, 0, 0);
      }
      if (l4 == 0) {
        float w = wcl[(wv*16 + l15)*NE + pe];
#pragma unroll
        for (int j = 0; j < NOUT; ++j)
          og[j] += w * (acc[j] + bo[pe*NOUT + j]);
      }
    }

    // ---- layer 1: h^T = relu(W1^T X^T + b1) -> bufC ----
    {
      f32x4 acc[4][2];
#pragma unroll
      for (int cf = 0; cf < 4; ++cf) {
        f32x4 bv = *reinterpret_cast<const f32x4*>(&b1[e*HD + wch*64 + cf*16 + l4*4]);
        acc[cf][0] = bv; acc[cf][1] = bv;
      }
      const unsigned short* fw1W = rf_ptr(fw1 + e*24576 + wch*6144) + lane*8;
#pragma unroll
      for (int kq = 0; kq < KQ1; ++kq) {
        bf16x8 aw[4];
        aw[0] = *(const bf16x8*)(fw1W + kq*1024);
        aw[1] = *(const bf16x8*)(fw1W + kq*1024 + 512);
        aw[2] = *(const bf16x8*)(fw1W + 3072 + kq*1024);
        aw[3] = *(const bf16x8*)(fw1W + 3072 + kq*1024 + 512);
#pragma unroll
        for (int pf = 0; pf < 2; ++pf) {
          bf16x8 bx;
          if constexpr (XSTAGED) {
            bx = *(const bf16x8*)(xsb + (pf*KQ1 + kq)*512);
          } else {
            const int p = perm[row0 + wpt*32 + pf*16 + l15];
            const int kb = kq*32 + l4*8;
            const float* src = x + (size_t)p*XC + 3;
#pragma unroll
            for (int j = 0; j < 8; ++j)
              bx[j] = (short)((kb + j < FIN) ? f2bf(src[kb + j]) : (unsigned short)0);
          }
#pragma unroll
          for (int cf = 0; cf < 4; ++cf)
            acc[cf][pf] = __builtin_amdgcn_mfma_f32_16x16x32_bf16(aw[cf], bx, acc[cf][pf], 0, 0, 0);
        }
      }
      store_hB(acc, bufC, wch, wpt, l15, l4);
    }
    __syncthreads();   // L1 writes done; also: all waves past L4 reads of bufP

    // ---- layer 2: bufC -> bufO ----
    layerH(bufC, bufO, fw2 + e*65536 + wch*16384, b2 + e*HD, wch, wpt, l15, l4, lane);
    __syncthreads();
    // ---- layer 3: bufO -> bufC ----
    layerH(bufO, bufC, fw3 + e*65536 + wch*16384, b3 + e*HD, wch, wpt, l15, l4, lane);
    __syncthreads();

    pe = e;
    pb = (bufC == hA) ? 0 : 1;
  }

  // ---- final pending L4 (no trailing barrier needed; og is per-thread) ----
  if (pe >= 0 && wv < 4) {
    unsigned short* bufP = (pb == 0) ? hA : hBuf;
    const unsigned short* fwoE = rf_ptr(fwo + pe*4096) + lane*8;
    f32x4 acc = {0.f, 0.f, 0.f, 0.f};
#pragma unroll
    for (int kq = 0; kq < KQH; ++kq) {
      bf16x8 aw = *(const bf16x8*)(fwoE + kq*512);
      bf16x8 bh = *(const bf16x8*)(bufP + wv*4096 + kq*512 + lane*8);
      acc = __builtin_amdgcn_mfma_f32_16x16x32_bf16(aw, bh, acc, 0, 0, 0);
    }
    if (l4 == 0) {
      float w = wcl[(wv*16 + l15)*NE + pe];
#pragma unroll
      for (int j = 0; j < NOUT; ++j)
        og[j] += w * (acc[j] + bo[pe*NOUT + j]);
    }
  }

  if (wv < 4 && l4 == 0) {
    const int p = perm[row0 + wv*16 + l15];
    f32x4 o = {og[0], og[1], og[2], og[3]};
    *reinterpret_cast<f32x4*>(&out[(size_t)p*NOUT]) = o;
  }
}

extern "C" void kernel_launch(void* const* d_in, const int* in_sizes, int n_in,
                              void* d_out, int out_size, void* d_ws, size_t ws_size,
                              hipStream_t stream) {
  const float* x    = (const float*)d_in[0];
  const float* cent = (const float*)d_in[1];
  const float* W1   = (const float*)d_in[2];
  const float* b1   = (const float*)d_in[3];
  const float* W2   = (const float*)d_in[4];
  const float* b2   = (const float*)d_in[5];
  const float* W3   = (const float*)d_in[6];
  const float* b3   = (const float*)d_in[7];
  const float* Wo   = (const float*)d_in[8];
  const float* bo   = (const float*)d_in[9];
  float* out = (float*)d_out;

  const int N = in_sizes[0] / XC;                 // 131072
  const int nfragX = (N/16) * KQ1;                // 24576 fragments

  // ws layout (bytes): [weights 2,555,904][perm 4N][rankmask 4N][counts 1K][offsets 1K][xs 25,165,824]
  unsigned short* wsb = (unsigned short*)d_ws;
  char* base = (char*)d_ws + (size_t)WTOT*2;
  int*          perm     = (int*)base;
  unsigned int* rankmask = (unsigned int*)(base + (size_t)4*N);
  int*          counts   = (int*)(base + (size_t)8*N);
  int*          offsets  = (int*)(base + (size_t)8*N + 1024);
  unsigned short* xs     = (unsigned short*)(base + (size_t)8*N + 2048);
  const size_t need_xs = (size_t)WTOT*2 + (size_t)8*N + 2048 + (size_t)nfragX*512*2;

  convert_weights<<<dim3((WTOT + 255) / 256), dim3(256), 0, stream>>>(W1, W2, W3, Wo, wsb, counts);
  gate_mask<<<dim3((N + 255) / 256), dim3(256), 0, stream>>>(x, cent, rankmask, counts, N);
  scan_offsets<<<dim3(1), dim3(256), 0, stream>>>(counts, offsets);
  scatter_perm<<<dim3((N + 255) / 256), dim3(256), 0, stream>>>(rankmask, offsets, perm, N);

  if (ws_size >= need_xs) {
    convert_x<<<dim3((nfragX*512 + 255) / 256), dim3(256), 0, stream>>>(x, xs, perm, nfragX);
    meganerf_fused<true><<<dim3(N / MT), dim3(NTHREADS), 0, stream>>>(
        x, cent, b1, b2, b3, bo, wsb, xs, perm, out);
  } else {
    meganerf_fused<false><<<dim3(N / MT), dim3(NTHREADS), 0, stream>>>(
        x, cent, b1, b2, b3, bo, wsb, wsb, perm, out);
  }
}

// Round 16
// 125.186 us; speedup vs baseline: 1.3125x; 1.3125x over previous
//
#include <hip/hip_runtime.h>
#include <hip/hip_bf16.h>
#include <stdint.h>

// MegaNeRF fused MoE-MLP for MI355X (gfx950).  Round 16.
// E=8 experts, MLP 90->256->256->256->4, N=131072 points, inverse-distance gating.
//
// Round-16: r15's retile REGRESSED (119 vs 104: weight-L2 doubling beat the
// LDS-read halving; operand reuse is pinned at 32 acc regs).  Revert fused to
// r14's verified wch(8)x64pt form, and delete the convert_x pre-pass: X
// fragments are staged into LDS once per block inside the fused kernel
// (expert-invariant, 12 KB), removing a dependent dispatch + 25 MB xs
// round-trip.  LDS ~80 KB -> still 2 blocks/CU.

#define NE    8
#define FIN   90
#define HD    256
#define NOUT  4
#define XC    93          // 3 + FIN columns in x

#define MT        64      // points per block
#define NTHREADS  512     // 8 waves: wch(8)

#define KQ1   3           // ceil(90/32) -> K padded to 96
#define KQH   8           // 256/32

#define W1_ELEMS (NE*8*KQ1*2*512)   // 196608
#define W2_ELEMS (NE*8*KQH*2*512)   // 524288
#define WO_ELEMS (NE*KQH*512)       // 32768  (OUT padded 4->16)
#define WTOT     (W1_ELEMS + 2*W2_ELEMS + WO_ELEMS)   // 1277952 elems

typedef __attribute__((ext_vector_type(8))) short bf16x8;
typedef __attribute__((ext_vector_type(4))) short bf16x4;
typedef __attribute__((ext_vector_type(4))) float f32x4;

__device__ __forceinline__ unsigned short f2bf(float f) {   // cold path only
  union { float f; uint32_t u; } v; v.f = f;
  v.u += 0x7fffu + ((v.u >> 16) & 1u);   // RNE
  return (unsigned short)(v.u >> 16);
}

__device__ __forceinline__ short relu_bf(float f) {         // hot epilogue
  __hip_bfloat16 t = __float2bfloat16(fmaxf(f, 0.f));
  return __builtin_bit_cast(short, t);
}

// wave-uniform pointer -> SGPR (HK technique: readfirstlane base hoisting)
__device__ __forceinline__ const unsigned short* rf_ptr(const unsigned short* p) {
  uint64_t u = (uint64_t)(uintptr_t)p;
  uint32_t lo = __builtin_amdgcn_readfirstlane((uint32_t)u);
  uint32_t hi = __builtin_amdgcn_readfirstlane((uint32_t)(u >> 32));
  return (const unsigned short*)(uintptr_t)(((uint64_t)hi << 32) | lo);
}

// ---------------------------------------------------------------------------
// Weight conversion (r10-r15, verified) + counts zeroing in block 0.
//   W1:    g = ((e*8 + wch)*3 + kq)*2 + cf ;  W2/W3: g = ((e*8+wch)*8+kq)*2+cf
//   Wo:    g = e*8 + kq
// elem (lane,j) = W[k = kq*32+(lane>>4)*8+j][n = wch*32 + cf*16 + (lane&15)].
// ---------------------------------------------------------------------------
__global__ __launch_bounds__(256)
void convert_weights(const float* __restrict__ W1, const float* __restrict__ W2,
                     const float* __restrict__ W3, const float* __restrict__ Wo,
                     unsigned short* __restrict__ ws, int* __restrict__ counts) {
  if (blockIdx.x == 0) counts[threadIdx.x] = 0;
  int idx = blockIdx.x * 256 + threadIdx.x;
  int j = idx & 7;
  int lane = (idx >> 3) & 63;
  int n16 = lane & 15;
  int kof = ((lane >> 4) << 3) + j;
  if (idx < W1_ELEMS) {
    int g = idx >> 9;
    int cf = g & 1; int t = g >> 1;
    int kq = t % 3; t /= 3;
    int wch = t & 7; int e = t >> 3;
    int n = wch*32 + cf*16 + n16, k = kq*32 + kof;
    float v = (k < FIN) ? W1[(e*FIN + k)*HD + n] : 0.f;
    ws[idx] = f2bf(v);
  } else if (idx < W1_ELEMS + 2*W2_ELEMS) {
    int u = idx - W1_ELEMS;
    const float* W = (u < W2_ELEMS) ? W2 : W3;
    int uu = (u < W2_ELEMS) ? u : (u - W2_ELEMS);
    int g = uu >> 9;
    int cf = g & 1; int t = g >> 1;
    int kq = t & 7; t >>= 3;
    int wch = t & 7; int e = t >> 3;
    int n = wch*32 + cf*16 + n16, k = kq*32 + kof;
    ws[idx] = f2bf(W[(e*HD + k)*HD + n]);
  } else if (idx < WTOT) {
    int t = idx - (W1_ELEMS + 2*W2_ELEMS);
    int g = t >> 9;
    int kq = g & 7; int e = g >> 3;
    int k = kq*32 + kof;
    float v = (n16 < NOUT) ? Wo[(e*HD + k)*NOUT + n16] : 0.f;
    ws[idx] = f2bf(v);
  }
}

// --------------------------- compaction pre-pass ---------------------------
// Per-block LDS histogram + one global atomic per nonzero bucket (G12).
__global__ __launch_bounds__(256)
void gate_mask(const float* __restrict__ x, const float* __restrict__ cent,
               unsigned int* __restrict__ rankmask, int* __restrict__ counts, int N) {
  __shared__ int lcnt[256];
  __shared__ int lbase[256];
  const int tid = threadIdx.x;
  const int p = blockIdx.x * 256 + tid;
  lcnt[tid] = 0;
  __syncthreads();

  unsigned int mask = 0; int lr = 0;
  if (p < N) {
    float px = x[(size_t)p*XC + 1], py = x[(size_t)p*XC + 2];
    float d[NE]; float mind = 3.4e38f;
#pragma unroll
    for (int e = 0; e < NE; ++e) {
      float dx = px - cent[e*3 + 1];
      float dy = py - cent[e*3 + 2];
      d[e] = __fsqrt_rn(__fmul_rn(dx, dx) + __fmul_rn(dy, dy));
      mind = fminf(mind, d[e]);
    }
    float m = 1.5f * mind;
#pragma unroll
    for (int e = 0; e < NE; ++e)
      if (!(d[e] > m)) mask |= (1u << e);        // same predicate as inv>0
    lr = atomicAdd(&lcnt[mask], 1);              // LDS atomic: fast
  }
  __syncthreads();
  if (lcnt[tid] > 0)
    lbase[tid] = atomicAdd(&counts[tid], lcnt[tid]);   // few per block, uncontended
  __syncthreads();
  if (p < N)
    rankmask[p] = ((unsigned int)(lbase[mask] + lr) << 8) | mask;
}

// Parallel bucket-offset scan, popcount-DESC order.
__global__ __launch_bounds__(256)
void scan_offsets(const int* __restrict__ counts, int* __restrict__ offsets) {
  __shared__ int cnt[256];
  __shared__ int key[256];
  const int m = threadIdx.x;
  cnt[m] = counts[m];
  key[m] = ((8 - __popc((unsigned)m)) << 8) | m;
  __syncthreads();
  const int my = key[m];
  int acc = 0;
  for (int i = 0; i < 256; ++i)
    if (key[i] < my) acc += cnt[i];
  offsets[m] = acc;
}

__global__ __launch_bounds__(256)
void scatter_perm(const unsigned int* __restrict__ rankmask,
                  const int* __restrict__ offsets, int* __restrict__ perm, int N) {
  int p = blockIdx.x * 256 + threadIdx.x;
  if (p >= N) return;
  unsigned int v = rankmask[p];
  perm[offsets[v & 255u] + (int)(v >> 8)] = p;
}

// ---------------------------------------------------------------------------
// Epilogue (r14 algebra, verified): relu + pack 4 channels -> one b64 store
// into [mtile pf][kq=wch-slot][lane'][8].  Conflict-free (4 bank phases).
// ---------------------------------------------------------------------------
__device__ __forceinline__ void store_hB(f32x4 (&acc)[2][4], unsigned short* dst,
                                         int wch, int l15, int l4) {
  unsigned short* base = dst + wch*512 + l15*8 + (l4>>1)*128 + (l4&1)*4;
#pragma unroll
  for (int cf = 0; cf < 2; ++cf)
#pragma unroll
    for (int pf = 0; pf < 4; ++pf) {
      bf16x4 s;
      s.x = relu_bf(acc[cf][pf][0]);
      s.y = relu_bf(acc[cf][pf][1]);
      s.z = relu_bf(acc[cf][pf][2]);
      s.w = relu_bf(acc[cf][pf][3]);
      *reinterpret_cast<bf16x4*>(base + pf*4096 + cf*256) = s;
    }
}

// One hidden layer src -> dst (ping-pong; caller places ONE barrier after).
__device__ __forceinline__ void layerH(const unsigned short* src, unsigned short* dst,
                                       const unsigned short* __restrict__ fw,
                                       const float* __restrict__ bias,
                                       int wch, int l15, int l4, int lane) {
  f32x4 acc[2][4];   // [cf][pf]
#pragma unroll
  for (int cf = 0; cf < 2; ++cf) {
    f32x4 bv = *reinterpret_cast<const f32x4*>(&bias[wch*32 + cf*16 + l4*4]);
#pragma unroll
    for (int pf = 0; pf < 4; ++pf)
      acc[cf][pf] = bv;
  }

  const unsigned short* fwW = rf_ptr(fw) + lane*8;   // SGPR base + lane off
  const unsigned short* rb  = src + lane*8;          // LDS, imm offsets
#pragma unroll
  for (int kq = 0; kq < KQH; ++kq) {
    bf16x8 aw0 = *(const bf16x8*)(fwW + kq*1024);
    bf16x8 aw1 = *(const bf16x8*)(fwW + kq*1024 + 512);
#pragma unroll
    for (int pf = 0; pf < 4; ++pf) {
      bf16x8 bh = *(const bf16x8*)(rb + pf*4096 + kq*512);
      acc[0][pf] = __builtin_amdgcn_mfma_f32_16x16x32_bf16(aw0, bh, acc[0][pf], 0, 0, 0);
      acc[1][pf] = __builtin_amdgcn_mfma_f32_16x16x32_bf16(aw1, bh, acc[1][pf], 0, 0, 0);
    }
  }
  store_hB(acc, dst, wch, l15, l4);
}

__global__ __launch_bounds__(NTHREADS)
void meganerf_fused(const float* __restrict__ x, const float* __restrict__ cent,
                    const float* __restrict__ b1, const float* __restrict__ b2,
                    const float* __restrict__ b3, const float* __restrict__ bo,
                    const unsigned short* __restrict__ wf,
                    const int* __restrict__ perm,
                    float* __restrict__ out) {
  __shared__ unsigned short hA[4 * KQH * 512];   // 32768 B: [mtile][kq][lane][8]
  __shared__ unsigned short hBuf[4 * KQH * 512]; // 32768 B (ping-pong partner)
  __shared__ unsigned short xF[4 * KQ1 * 512];   // 12288 B: staged X fragments
  __shared__ float wcl[MT * NE];                 // 2048 B
  __shared__ int flags[NE];                      // block-uniform expert flags

  const int tid = threadIdx.x;
  const int lane = tid & 63;
  const int wv = tid >> 6;      // 0..7
  const int wch = wv;           // channel group 0..7 (32 channels each)
  const int l15 = lane & 15, l4 = lane >> 4;
  const int row0 = blockIdx.x * MT;

  if (tid < NE) flags[tid] = 0;
  __syncthreads();

  // --- cluster weights (strict IEEE f32, no contraction: must bit-match np) ---
  if (tid < MT) {
    const int p = perm[row0 + tid];
    float px = x[(size_t)p*XC + 1], py = x[(size_t)p*XC + 2];
    float d[NE]; float mind = 3.4e38f;
#pragma unroll
    for (int e = 0; e < NE; ++e) {
      float dx = px - cent[e*3 + 1];
      float dy = py - cent[e*3 + 2];
      d[e] = __fsqrt_rn(__fmul_rn(dx, dx) + __fmul_rn(dy, dy));
      mind = fminf(mind, d[e]);
    }
    float m = 1.5f * mind, s = 0.f, inv[NE];
#pragma unroll
    for (int e = 0; e < NE; ++e) {
      float iv = (d[e] > m) ? 0.f : 1.f / (d[e] + 1e-8f);
      inv[e] = iv; s += iv;
    }
#pragma unroll
    for (int e = 0; e < NE; ++e) {
      wcl[tid*NE + e] = inv[e] / s;
      if (inv[e] > 0.f) flags[e] = 1;   // benign same-value race
    }
  }

  // --- stage X fragments into LDS (expert-invariant; replaces convert_x) ---
  // slot s in [0, 12*64): frag f = s>>6 (pf = f/KQ1, kq = f%KQ1), lane_s = s&63.
  // elem (lane_s, j) = X[perm[row0 + pf*16 + (lane_s&15)]][kq*32+(lane_s>>4)*8+j]
  for (int s = tid; s < 4*KQ1*64; s += NTHREADS) {
    const int f = s >> 6, ls = s & 63;
    const int pf = f / KQ1, kq = f - pf*KQ1;
    const int p = perm[row0 + pf*16 + (ls & 15)];
    const int kb = kq*32 + ((ls >> 4) << 3);
    const float* src = x + (size_t)p*XC + 3;
    bf16x8 v;
#pragma unroll
    for (int j = 0; j < 8; ++j)
      v[j] = (short)((kb + j < FIN) ? f2bf(src[kb + j]) : (unsigned short)0);
    *(bf16x8*)(xF + (size_t)f*512 + ls*8) = v;
  }
  __syncthreads();

  const unsigned short* fw1 = wf;
  const unsigned short* fw2 = wf + W1_ELEMS;
  const unsigned short* fw3 = fw2 + W2_ELEMS;
  const unsigned short* fwo = fw3 + W2_ELEMS;
  const unsigned short* xfb = xF + lane*8;   // LDS base, imm frag offsets

  float og[NOUT] = {0.f, 0.f, 0.f, 0.f};   // gated outputs (waves 0-3, l4==0)
  int pe = -1;                             // pending expert awaiting its L4
  int pb = 0;                              // buffer index holding pending h

  for (int e = 0; e < NE; ++e) {
    if (!flags[e]) continue;               // block-uniform: exact zero contribution

    unsigned short* bufP = (pb == 0) ? hA : hBuf;    // pending L4 input
    unsigned short* bufC = (pe >= 0) ? ((pb == 0) ? hBuf : hA) : hA;  // L1 output
    unsigned short* bufO = (bufC == hA) ? hBuf : hA; // L2 output

    // ---- L4(pending) on waves 0-3 (reads bufP)  OVERLAPPED with
    //      L1(e) on all waves (writes bufC != bufP): no barrier between ----
    if (pe >= 0 && wv < 4) {
      const unsigned short* fwoE = rf_ptr(fwo + pe*4096) + lane*8;
      f32x4 acc = {0.f, 0.f, 0.f, 0.f};
#pragma unroll
      for (int kq = 0; kq < KQH; ++kq) {
        bf16x8 aw = *(const bf16x8*)(fwoE + kq*512);
        bf16x8 bh = *(const bf16x8*)(bufP + wv*4096 + kq*512 + lane*8);
        acc = __builtin_amdgcn_mfma_f32_16x16x32_bf16(aw, bh, acc, 0, 0, 0);
      }
      if (l4 == 0) {
        float w = wcl[(wv*16 + l15)*NE + pe];
#pragma unroll
        for (int j = 0; j < NOUT; ++j)
          og[j] += w * (acc[j] + bo[pe*NOUT + j]);
      }
    }

    // ---- layer 1: h^T = relu(W1^T X^T + b1) -> bufC (X frags from LDS) ----
    {
      f32x4 acc[2][4];
#pragma unroll
      for (int cf = 0; cf < 2; ++cf) {
        f32x4 bv = *reinterpret_cast<const f32x4*>(&b1[e*HD + wch*32 + cf*16 + l4*4]);
#pragma unroll
        for (int pf = 0; pf < 4; ++pf)
          acc[cf][pf] = bv;
      }
      const unsigned short* fw1W = rf_ptr(fw1 + e*24576 + wch*3072) + lane*8;
#pragma unroll
      for (int kq = 0; kq < KQ1; ++kq) {
        bf16x8 aw0 = *(const bf16x8*)(fw1W + kq*1024);
        bf16x8 aw1 = *(const bf16x8*)(fw1W + kq*1024 + 512);
#pragma unroll
        for (int pf = 0; pf < 4; ++pf) {
          bf16x8 bx = *(const bf16x8*)(xfb + (pf*KQ1 + kq)*512);
          acc[0][pf] = __builtin_amdgcn_mfma_f32_16x16x32_bf16(aw0, bx, acc[0][pf], 0, 0, 0);
          acc[1][pf] = __builtin_amdgcn_mfma_f32_16x16x32_bf16(aw1, bx, acc[1][pf], 0, 0, 0);
        }
      }
      store_hB(acc, bufC, wch, l15, l4);
    }
    __syncthreads();   // L1 writes done; also: all waves past L4 reads of bufP

    // ---- layer 2: bufC -> bufO ----
    layerH(bufC, bufO, fw2 + e*65536 + wch*8192, b2 + e*HD, wch, l15, l4, lane);
    __syncthreads();
    // ---- layer 3: bufO -> bufC ----
    layerH(bufO, bufC, fw3 + e*65536 + wch*8192, b3 + e*HD, wch, l15, l4, lane);
    __syncthreads();

    pe = e;
    pb = (bufC == hA) ? 0 : 1;
  }

  // ---- final pending L4 (no trailing barrier needed; og is per-thread) ----
  if (pe >= 0 && wv < 4) {
    unsigned short* bufP = (pb == 0) ? hA : hBuf;
    const unsigned short* fwoE = rf_ptr(fwo + pe*4096) + lane*8;
    f32x4 acc = {0.f, 0.f, 0.f, 0.f};
#pragma unroll
    for (int kq = 0; kq < KQH; ++kq) {
      bf16x8 aw = *(const bf16x8*)(fwoE + kq*512);
      bf16x8 bh = *(const bf16x8*)(bufP + wv*4096 + kq*512 + lane*8);
      acc = __builtin_amdgcn_mfma_f32_16x16x32_bf16(aw, bh, acc, 0, 0, 0);
    }
    if (l4 == 0) {
      float w = wcl[(wv*16 + l15)*NE + pe];
#pragma unroll
      for (int j = 0; j < NOUT; ++j)
        og[j] += w * (acc[j] + bo[pe*NOUT + j]);
    }
  }

  if (wv < 4 && l4 == 0) {
    const int p = perm[row0 + wv*16 + l15];
    f32x4 o = {og[0], og[1], og[2], og[3]};
    *reinterpret_cast<f32x4*>(&out[(size_t)p*NOUT]) = o;
  }
}

extern "C" void kernel_launch(void* const* d_in, const int* in_sizes, int n_in,
                              void* d_out, int out_size, void* d_ws, size_t ws_size,
                              hipStream_t stream) {
  const float* x    = (const float*)d_in[0];
  const float* cent = (const float*)d_in[1];
  const float* W1   = (const float*)d_in[2];
  const float* b1   = (const float*)d_in[3];
  const float* W2   = (const float*)d_in[4];
  const float* b2   = (const float*)d_in[5];
  const float* W3   = (const float*)d_in[6];
  const float* b3   = (const float*)d_in[7];
  const float* Wo   = (const float*)d_in[8];
  const float* bo   = (const float*)d_in[9];
  float* out = (float*)d_out;

  const int N = in_sizes[0] / XC;                 // 131072

  // ws layout (bytes): [weights 2,555,904][perm 4N][rankmask 4N][counts 1K][offsets 1K]
  unsigned short* wsb = (unsigned short*)d_ws;
  char* base = (char*)d_ws + (size_t)WTOT*2;
  int*          perm     = (int*)base;
  unsigned int* rankmask = (unsigned int*)(base + (size_t)4*N);
  int*          counts   = (int*)(base + (size_t)8*N);
  int*          offsets  = (int*)(base + (size_t)8*N + 1024);

  convert_weights<<<dim3((WTOT + 255) / 256), dim3(256), 0, stream>>>(W1, W2, W3, Wo, wsb, counts);
  gate_mask<<<dim3((N + 255) / 256), dim3(256), 0, stream>>>(x, cent, rankmask, counts, N);
  scan_offsets<<<dim3(1), dim3(256), 0, stream>>>(counts, offsets);
  scatter_perm<<<dim3((N + 255) / 256), dim3(256), 0, stream>>>(rankmask, offsets, perm, N);
  meganerf_fused<<<dim3(N / MT), dim3(NTHREADS), 0, stream>>>(
      x, cent, b1, b2, b3, bo, wsb, perm, out);
}